// Round 1
// baseline (2206.747 us; speedup 1.0000x reference)
//
#include <hip/hip_runtime.h>

#define NN 50000
#define EE 800000
#define DD 128
#define RR 8
#define BB 2

__global__ void zero_f32(float* __restrict__ p, int n) {
    int i = blockIdx.x * blockDim.x + threadIdx.x;
    if (i < n) p[i] = 0.f;
}

__global__ void count_edges(const int* __restrict__ dst, const int* __restrict__ et,
                            float* __restrict__ cnt) {
    int e = blockIdx.x * blockDim.x + threadIdx.x;
    if (e < EE) atomicAdd(&cnt[dst[e] * RR + et[e]], 1.0f);
}

__global__ void invert_cnt(float* __restrict__ cnt) {
    int i = blockIdx.x * blockDim.x + threadIdx.x;
    if (i < NN * RR) cnt[i] = 1.0f / fmaxf(cnt[i], 1.0f);
}

// out[n, j] = bias[j] + sum_i in[n, i] * root[i, j]   (full write, no accumulate)
__global__ __launch_bounds__(128) void root_bias(const float* __restrict__ in,
                                                 const float* __restrict__ root,
                                                 const float* __restrict__ bias,
                                                 float* __restrict__ out) {
    __shared__ float xr[DD];
    int n = blockIdx.x, j = threadIdx.x;
    xr[j] = in[n * DD + j];
    __syncthreads();
    float acc = bias[j];
#pragma unroll 16
    for (int i = 0; i < DD; ++i) acc = fmaf(xr[i], root[i * DD + j], acc);
    out[n * DD + j] = acc;
}

// One 128-thread block per edge. Thread j computes output dim j:
//   y_j = sum_c x[src, b*64+c] * W[et, b, c, jj],  b = j/64, jj = j%64
// then atomically adds y_j * (1/cnt[dst, et]) into out[dst, j].
__global__ __launch_bounds__(128) void edge_scatter(const float* __restrict__ x,
                                                    const int* __restrict__ src,
                                                    const int* __restrict__ dst,
                                                    const int* __restrict__ et,
                                                    const float* __restrict__ W,
                                                    const float* __restrict__ inv,
                                                    float* __restrict__ out) {
    int e = blockIdx.x, j = threadIdx.x;
    int b = j >> 6, jj = j & 63;
    int s = src[e], d = dst[e], r = et[e];
    __shared__ float xs[DD];
    xs[j] = x[s * DD + j];
    __syncthreads();
    const float* Wb = W + ((r * BB + b) * 64 * 64);  // [c][jj] row-major
    float acc = 0.f;
#pragma unroll 16
    for (int c = 0; c < 64; ++c) acc = fmaf(xs[b * 64 + c], Wb[c * 64 + jj], acc);
    atomicAdd(&out[d * DD + j], acc * inv[d * RR + r]);
}

__global__ void relu_k(float* __restrict__ p, int n) {
    int i = blockIdx.x * blockDim.x + threadIdx.x;
    if (i < n) p[i] = fmaxf(p[i], 0.f);
}

extern "C" void kernel_launch(void* const* d_in, const int* in_sizes, int n_in,
                              void* d_out, int out_size, void* d_ws, size_t ws_size,
                              hipStream_t stream) {
    const float* x     = (const float*)d_in[0];
    const int*   ei    = (const int*)d_in[1];
    const int*   src   = ei;        // edge_index[0, :]
    const int*   dstp  = ei + EE;   // edge_index[1, :]
    const int*   et    = (const int*)d_in[2];
    const float* W1    = (const float*)d_in[3];
    const float* root1 = (const float*)d_in[4];
    const float* b1    = (const float*)d_in[5];
    const float* W2    = (const float*)d_in[6];
    const float* root2 = (const float*)d_in[7];
    const float* b2    = (const float*)d_in[8];
    float* out = (float*)d_out;

    float* cnt = (float*)d_ws;      // N*R floats: counts, then inverted in place
    float* h   = cnt + NN * RR;     // N*D floats: layer-1 activations

    // counts -> 1/max(cnt,1)
    zero_f32<<<(NN * RR + 255) / 256, 256, 0, stream>>>(cnt, NN * RR);
    count_edges<<<(EE + 255) / 256, 256, 0, stream>>>(dstp, et, cnt);
    invert_cnt<<<(NN * RR + 255) / 256, 256, 0, stream>>>(cnt);

    // layer 1: h = relu(x @ root1 + b1 + scatter(W1 blockdiag mean agg))
    root_bias<<<NN, DD, 0, stream>>>(x, root1, b1, h);
    edge_scatter<<<EE, DD, 0, stream>>>(x, src, dstp, et, W1, cnt, h);
    relu_k<<<(NN * DD + 255) / 256, 256, 0, stream>>>(h, NN * DD);

    // layer 2: out = h @ root2 + b2 + scatter(W2 blockdiag mean agg)
    root_bias<<<NN, DD, 0, stream>>>(h, root2, b2, out);
    edge_scatter<<<EE, DD, 0, stream>>>(h, src, dstp, et, W2, cnt, out);
}